// Round 8
// baseline (99.597 us; speedup 1.0000x reference)
//
#include <hip/hip_runtime.h>

#define B   32
#define C   512
#define HID 32
#define HW  3136        // 56*56
#define HW4 784         // HW/4
#define POS 410         // round(0.8*512); threshold = sorted[POS-1]

typedef float f32x4 __attribute__((ext_vector_type(4)));

struct V4 { f32x4 a, b, c, d; };

__device__ inline V4 load_ch(const f32x4* __restrict__ xp, int tid, bool tail) {
    V4 r;
    r.a = xp[tid];
    r.b = xp[tid + 256];
    r.c = xp[tid + 512];
    r.d = (f32x4){0.f, 0.f, 0.f, 0.f};
    if (tail) r.d = xp[tid + 768];
    return r;
}

__device__ inline float sum16(const V4& v) {
    return (v.a.x + v.a.y) + (v.a.z + v.a.w)
         + (v.b.x + v.b.y) + (v.b.z + v.b.w)
         + (v.c.x + v.c.y) + (v.c.z + v.c.w)
         + (v.d.x + v.d.y) + (v.d.z + v.d.w);
}

// ---------------------------------------------------------------------------
// K1: fused copy + per-channel mean. 2048 blocks x 256 threads, 8 channels
// per block (bc = bid + 2048*k). HOT LOOP HAS NO BARRIER AND NO LDS:
// __syncthreads on gfx950 drains vmcnt(0) (all loads+stores), which killed
// R7's pipeline. Per-thread partials for all 8 channels live in registers;
// one LDS reduce + single barrier at the end. Plain loads, NT stores.
// ---------------------------------------------------------------------------
__global__ __launch_bounds__(256) void copy_mean_kernel(const float* __restrict__ x,
                                                        float* __restrict__ out,
                                                        float* __restrict__ means) {
    const int tid  = threadIdx.x;
    const bool tail = tid < (HW4 - 3 * 256);      // 16 threads take a 4th vec
    float psum[8];

    int bc = blockIdx.x;
    V4 v = load_ch(reinterpret_cast<const f32x4*>(x + (size_t)bc * HW), tid, tail);

    #pragma unroll
    for (int k = 0; k < 8; ++k) {
        V4 n;
        if (k < 7)                                 // prefetch next channel
            n = load_ch(reinterpret_cast<const f32x4*>(x + (size_t)(bc + 2048) * HW), tid, tail);

        f32x4* op = reinterpret_cast<f32x4*>(out + (size_t)bc * HW);
        __builtin_nontemporal_store(v.a, op + tid);
        __builtin_nontemporal_store(v.b, op + tid + 256);
        __builtin_nontemporal_store(v.c, op + tid + 512);
        if (tail) __builtin_nontemporal_store(v.d, op + tid + 768);

        psum[k] = sum16(v);
        v = n;
        bc += 2048;
    }

    // end-of-kernel reduction: 8 wave-shuffle reduces, ONE barrier.
    __shared__ float red[4][8];
    const int wave = tid >> 6;
    const int lane = tid & 63;
    #pragma unroll
    for (int k = 0; k < 8; ++k) {
        float s = psum[k];
        #pragma unroll
        for (int off = 32; off > 0; off >>= 1)
            s += __shfl_down(s, off, 64);
        if (lane == 0) red[wave][k] = s;
    }
    __syncthreads();
    if (tid < 8) {
        float t = ((red[0][tid] + red[1][tid]) + (red[2][tid] + red[3][tid]));
        means[blockIdx.x + tid * 2048] = t * (1.0f / HW);
    }
}

// ---------------------------------------------------------------------------
// K2: SE excitation + rank-select threshold + mask. grid = B, block = C.
// ---------------------------------------------------------------------------
__global__ __launch_bounds__(512) void se_kernel(const float* __restrict__ means,
                                                 const float* __restrict__ W1,
                                                 const float* __restrict__ W2,
                                                 float* __restrict__ masks) {
    const int b = blockIdx.x;
    const int t = threadIdx.x;          // 0..511
    __shared__ float m[C];
    __shared__ float y1[HID];
    __shared__ float y2[C];
    __shared__ float thr;

    m[t] = means[b * C + t];
    __syncthreads();

    // W1 dot: 16 lanes per hidden unit (h = t>>4, l = t&15), shfl_xor reduce.
    {
        const int h = t >> 4;
        const int l = t & 15;
        const float* w = W1 + h * C;
        float acc = 0.f;
        for (int c = l; c < C; c += 16) acc = fmaf(m[c], w[c], acc);
        #pragma unroll
        for (int off = 8; off > 0; off >>= 1) acc += __shfl_xor(acc, off, 16);
        if (l == 0) y1[h] = fmaxf(acc, 0.f);
    }
    __syncthreads();

    {
        const float* w = W2 + t * HID;
        float acc = 0.f;
        #pragma unroll
        for (int h = 0; h < HID; ++h) acc = fmaf(y1[h], w[h], acc);
        y2[t] = 1.f / (1.f + expf(-acc));
    }
    __syncthreads();

    // rank with index tie-break: exactly one thread has rank == POS-1
    const float v = y2[t];
    int rank = 0;
    for (int j = 0; j < C; ++j) {
        float u = y2[j];                 // broadcast LDS read
        rank += (u < v || (u == v && j < t)) ? 1 : 0;
    }
    if (rank == POS - 1) thr = v;
    __syncthreads();

    masks[b * C + t] = (v <= thr) ? 1.f : 0.f;
}

// ---------------------------------------------------------------------------
// K3: zero-fill masked channels. One wave per channel, 4 channels/block.
// ~20% of waves write 12.25 KB of zeros; rest exit. Pure-write ~41 MB.
// ---------------------------------------------------------------------------
__global__ __launch_bounds__(256) void zero_kernel(const float* __restrict__ masks,
                                                   float* __restrict__ out) {
    const int wave = threadIdx.x >> 6;
    const int lane = threadIdx.x & 63;
    const int bc   = blockIdx.x * 4 + wave;
    if (masks[bc] != 0.f) return;
    f32x4* op = reinterpret_cast<f32x4*>(out + (size_t)bc * HW);
    const f32x4 z = {0.f, 0.f, 0.f, 0.f};
    for (int i = lane; i < HW4; i += 64)
        __builtin_nontemporal_store(z, op + i);
}

extern "C" void kernel_launch(void* const* d_in, const int* in_sizes, int n_in,
                              void* d_out, int out_size, void* d_ws, size_t ws_size,
                              hipStream_t stream) {
    const float* x  = (const float*)d_in[0];
    const float* W1 = (const float*)d_in[1];
    const float* W2 = (const float*)d_in[2];
    float* out = (float*)d_out;

    float* means = (float*)d_ws;                 // B*C floats = 64 KB
    float* masks = means + B * C;                // B*C floats = 64 KB

    copy_mean_kernel<<<2048, 256, 0, stream>>>(x, out, means);
    se_kernel<<<B, C, 0, stream>>>(means, W1, W2, masks);
    zero_kernel<<<B * C / 4, 256, 0, stream>>>(masks, out);
}